// Round 7
// baseline (441.100 us; speedup 1.0000x reference)
//
#include <hip/hip_runtime.h>
#include <hip/hip_bf16.h>

#define TB 256

typedef __attribute__((ext_vector_type(8))) short bf16x8;
typedef __attribute__((ext_vector_type(4))) float f32x4;

// 8 consecutive fp32 -> bf16x8 (RNE); compiler emits v_cvt_pk_bf16_f32 pairs
static __device__ inline bf16x8 cvt8(f32x4 lo, f32x4 hi) {
    union { bf16x8 v; __hip_bfloat162 h[4]; } u;
    u.h[0] = __float22bfloat162_rn(float2{lo[0], lo[1]});
    u.h[1] = __float22bfloat162_rn(float2{lo[2], lo[3]});
    u.h[2] = __float22bfloat162_rn(float2{hi[0], hi[1]});
    u.h[3] = __float22bfloat162_rn(float2{hi[2], hi[3]});
    return u.v;
}

// Zero-LDS direct-fragment GEMM.
// Key fact: X[*,512] and W[C_out,512] are both K-contiguous, and the
// mfma_f32_16x16x32_bf16 A/B fragment is 8 contiguous K-elems per lane
// (row=lane&15, k=(lane>>4)*8). So each fragment is a 32-B contiguous
// per-lane global load (pair of dwordx4) — full cache-line density, no
// LDS staging, no barriers. Waves are fully independent; the compiler
// software-pipelines the unrolled K-loop without any barrier drains.
// Reuse: 2 waves/block share A lines and 2 share B lines via L1; the 4
// n-tile blocks of an X panel sit on one XCD (swizzle) so L2 serves the
// X re-reads; W (1 MB/batch) is L2-resident.
__global__ __launch_bounds__(TB) void bgemm_bt_bias(
    const float* __restrict__ X,     // [8, 8192, 512]
    const float* __restrict__ Wt,    // [8, 512, 512]
    const float* __restrict__ Bias,  // [8, 512]
    float* __restrict__ Out)         // [8, 8192, 512]
{
    // XCD-aware swizzle: 4 n-tiles sharing an x-panel land on one XCD
    const int flat  = blockIdx.x;          // 0..2047
    const int xcd   = flat & 7;
    const int rr    = flat >> 3;
    const int nt    = rr & 3;
    const int p     = rr >> 2;
    const int panel = p * 8 + xcd;         // 0..511 = batch*64 + mtile
    const int mt    = panel & 63;
    const int b     = panel >> 6;

    const int m0  = mt * 128;
    const int n0  = nt * 128;
    const int tid = threadIdx.x;
    const int lane = tid & 63;
    const int wave = tid >> 6;
    const int wm = (wave >> 1) * 64;       // waves {0,1} m-half 0, {2,3} m-half 1
    const int wn = (wave & 1) * 64;        // waves {0,2} n-half 0, {1,3} n-half 1

    const int frow = lane & 15;            // fragment row (m for A, n for B)
    const int fk   = (lane >> 4) * 8;      // fragment k-offset (0,8,16,24)

    // per-fragment base pointers (compile-time-indexed under full unroll;
    // K-step advances via the 13-bit immediate offset: ks*128 B <= 1952)
    const float* xr[4];
    const float* wr[4];
#pragma unroll
    for (int mf = 0; mf < 4; ++mf)
        xr[mf] = X + ((size_t)b * 8192 + m0 + wm + mf * 16 + frow) * 512 + fk;
#pragma unroll
    for (int nf = 0; nf < 4; ++nf)
        wr[nf] = Wt + ((size_t)b * 512 + n0 + wn + nf * 16 + frow) * 512 + fk;

    f32x4 acc[4][4];
#pragma unroll
    for (int i = 0; i < 4; ++i)
#pragma unroll
        for (int j = 0; j < 4; ++j)
            acc[i][j] = (f32x4){0.f, 0.f, 0.f, 0.f};

#pragma unroll
    for (int ks = 0; ks < 16; ++ks) {
        bf16x8 af[4], bfr[4];
#pragma unroll
        for (int mf = 0; mf < 4; ++mf) {
            f32x4 lo = *(const f32x4*)(xr[mf] + ks * 32);
            f32x4 hi = *(const f32x4*)(xr[mf] + ks * 32 + 4);
            af[mf] = cvt8(lo, hi);
        }
#pragma unroll
        for (int nf = 0; nf < 4; ++nf) {
            f32x4 lo = *(const f32x4*)(wr[nf] + ks * 32);
            f32x4 hi = *(const f32x4*)(wr[nf] + ks * 32 + 4);
            bfr[nf] = cvt8(lo, hi);
        }
#pragma unroll
        for (int mf = 0; mf < 4; ++mf)
#pragma unroll
            for (int nf = 0; nf < 4; ++nf)
                acc[mf][nf] = __builtin_amdgcn_mfma_f32_16x16x32_bf16(
                    af[mf], bfr[nf], acc[mf][nf], 0, 0, 0);
    }

    // ---- epilogue: add bias, store fp32 ----
    float bv[4];
    const float* biasp = Bias + (size_t)b * 512 + n0 + wn;
#pragma unroll
    for (int nf = 0; nf < 4; ++nf)
        bv[nf] = biasp[nf * 16 + frow];

    float* outp = Out + ((size_t)b * 8192 + m0 + wm) * 512 + n0 + wn;
    const int orow = (lane >> 4) * 4;   // C/D: row = (lane>>4)*4 + reg
#pragma unroll
    for (int mf = 0; mf < 4; ++mf)
#pragma unroll
        for (int nf = 0; nf < 4; ++nf)
#pragma unroll
            for (int r = 0; r < 4; ++r)
                outp[(size_t)(mf * 16 + orow + r) * 512 + nf * 16 + frow] =
                    acc[mf][nf][r] + bv[nf];
}

extern "C" void kernel_launch(void* const* d_in, const int* in_sizes, int n_in,
                              void* d_out, int out_size, void* d_ws, size_t ws_size,
                              hipStream_t stream) {
    const float* X    = (const float*)d_in[0];
    const float* Wt   = (const float*)d_in[1];
    const float* Bias = (const float*)d_in[2];
    float* Out        = (float*)d_out;

    dim3 grid(2048);
    bgemm_bt_bias<<<grid, TB, 0, stream>>>(X, Wt, Bias, Out);
}

// Round 8
// 291.963 us; speedup vs baseline: 1.5108x; 1.5108x over previous
//
#include <hip/hip_runtime.h>
#include <hip/hip_bf16.h>

#define TB 256

typedef __attribute__((ext_vector_type(8))) short bf16x8;
typedef __attribute__((ext_vector_type(4))) float f32x4;

// async global->LDS, 16B per lane (m97 pattern: dest is wave-uniform base,
// HW adds lane*16; the GLOBAL address is per-lane, which is what lets us
// bake the bank-swizzle into the source permutation)
static __device__ __forceinline__ void gload_lds16(const float* g, float* l) {
    __builtin_amdgcn_global_load_lds(
        (const __attribute__((address_space(1))) void*)g,
        (__attribute__((address_space(3))) void*)l, 16, 0, 0);
}

// 8 consecutive fp32 -> bf16x8 (RNE); compiler emits v_cvt_pk_bf16_f32 pairs
static __device__ __forceinline__ bf16x8 cvt8(f32x4 lo, f32x4 hi) {
    union { bf16x8 v; __hip_bfloat162 h[4]; } u;
    u.h[0] = __float22bfloat162_rn(float2{lo[0], lo[1]});
    u.h[1] = __float22bfloat162_rn(float2{lo[2], lo[3]});
    u.h[2] = __float22bfloat162_rn(float2{hi[0], hi[1]});
    u.h[3] = __float22bfloat162_rn(float2{hi[2], hi[3]});
    return u.v;
}

// fp32-in-LDS GEMM with async staging.
// Staging chain of the 120us baseline (load->wait->cvt->ds_write->barrier) is
// replaced by fire-and-forget global_load_lds of raw fp32; fp32->bf16 convert
// moves to the fragment-read path where it pipelines with MFMA. The barrier's
// vmcnt drain now has the whole interval's compute to cover HBM latency.
//
// LDS tiles are [128][32] fp32 = 128B rows = exactly 32 banks, so reads would
// be 16-way bank-conflicted and global_load_lds forbids padding. Fix (rule 21,
// both-sides swizzle): physical 16B-slot = logical_slot ^ (row&7).
//  - write side: linear dest; lane l lands at (row=base+(l>>3), slot=l&7), so
//    its GLOBAL fetch is permuted to col-slot (l&7)^(l>>3)  [row&7 == l>>3]
//  - read side: same XOR on the slot index.
// Each consecutive-8-lane phase then covers all 32 banks: conflict-free.
__global__ __launch_bounds__(TB) void bgemm_bt_bias(
    const float* __restrict__ X,     // [8, 8192, 512]
    const float* __restrict__ Wt,    // [8, 512, 512]
    const float* __restrict__ Bias,  // [8, 512]
    float* __restrict__ Out)         // [8, 8192, 512]
{
    // XCD-aware swizzle: 4 n-tiles sharing an x-panel land on one XCD
    const int flat  = blockIdx.x;          // 0..2047
    const int xcd   = flat & 7;
    const int rr    = flat >> 3;
    const int nt    = rr & 3;
    const int p     = rr >> 2;
    const int panel = p * 8 + xcd;         // 0..511 = batch*64 + mtile
    const int mt    = panel & 63;
    const int b     = panel >> 6;

    const int m0  = mt * 128;
    const int n0  = nt * 128;
    const int tid = threadIdx.x;
    const int lane = tid & 63;
    const int wave = tid >> 6;
    const int wm = (wave >> 1) * 64;
    const int wn = (wave & 1) * 64;

    const int frow = lane & 15;            // fragment row (m for A, n for B)
    const int s0   = (lane >> 4) * 2;      // fragment 16B-slot pair base (k/4)

    __shared__ float As[2][128 * 32];
    __shared__ float Bs[2][128 * 32];

    // staging geometry: wave w stages rows w*32 .. w*32+31 (4 rounds of 8 rows)
    const int srow  = wave * 32 + (lane >> 3);      // round-0 row this lane feeds
    const int sslot = (lane & 7) ^ (lane >> 3);     // pre-swizzled global col-slot

    const float* xlane = X  + ((size_t)b * 8192 + m0 + srow) * 512 + sslot * 4;
    const float* wlane = Wt + ((size_t)b * 512  + n0 + srow) * 512 + sslot * 4;

#define STAGE(buf, kk) do {                                                     \
    _Pragma("unroll")                                                           \
    for (int i = 0; i < 4; ++i) {                                               \
        gload_lds16(xlane + (size_t)i * 8 * 512 + (kk), &As[buf][(wave * 32 + i * 8) * 32]); \
        gload_lds16(wlane + (size_t)i * 8 * 512 + (kk), &Bs[buf][(wave * 32 + i * 8) * 32]); \
    }                                                                           \
} while (0)

    // ---- prologue: tile 0 -> buf 0 ----
    STAGE(0, 0);
    __syncthreads();

    f32x4 acc[4][4];
#pragma unroll
    for (int i = 0; i < 4; ++i)
#pragma unroll
        for (int j = 0; j < 4; ++j)
            acc[i][j] = (f32x4){0.f, 0.f, 0.f, 0.f};

    const int KSTEPS = 16;
#pragma unroll 2
    for (int ks = 0; ks < KSTEPS; ++ks) {
        const int cur = ks & 1;
        const int nxt = cur ^ 1;

        // fire-and-forget prefetch of next tile; pinned before the compute
        // so the loads lead the interval
        if (ks + 1 < KSTEPS) STAGE(nxt, (ks + 1) * 32);
        __builtin_amdgcn_sched_barrier(0);

        bf16x8 af[4], bfr[4];
#pragma unroll
        for (int mf = 0; mf < 4; ++mf) {
            const int r = wm + mf * 16 + frow;
            const int rx = r & 7;
            const float* bp = &As[cur][r * 32];
            f32x4 lo = *(const f32x4*)(bp + ((s0 ^ rx) << 2));
            f32x4 hi = *(const f32x4*)(bp + (((s0 + 1) ^ rx) << 2));
            af[mf] = cvt8(lo, hi);
        }
#pragma unroll
        for (int nf = 0; nf < 4; ++nf) {
            const int r = wn + nf * 16 + frow;
            const int rx = r & 7;
            const float* bp = &Bs[cur][r * 32];
            f32x4 lo = *(const f32x4*)(bp + ((s0 ^ rx) << 2));
            f32x4 hi = *(const f32x4*)(bp + (((s0 + 1) ^ rx) << 2));
            bfr[nf] = cvt8(lo, hi);
        }

#pragma unroll
        for (int mf = 0; mf < 4; ++mf)
#pragma unroll
            for (int nf = 0; nf < 4; ++nf)
                acc[mf][nf] = __builtin_amdgcn_mfma_f32_16x16x32_bf16(
                    af[mf], bfr[nf], acc[mf][nf], 0, 0, 0);

        // barrier (with its vmcnt drain) makes nxt's async stores visible to
        // all waves and protects cur from being restaged at ks+1
        __syncthreads();
    }
#undef STAGE

    // ---- epilogue: add bias, store fp32 ----
    float bv[4];
    const float* biasp = Bias + (size_t)b * 512 + n0 + wn;
#pragma unroll
    for (int nf = 0; nf < 4; ++nf)
        bv[nf] = biasp[nf * 16 + frow];

    float* outp = Out + ((size_t)b * 8192 + m0 + wm) * 512 + n0 + wn;
    const int orow = (lane >> 4) * 4;   // C/D: row = (lane>>4)*4 + reg
#pragma unroll
    for (int mf = 0; mf < 4; ++mf)
#pragma unroll
        for (int nf = 0; nf < 4; ++nf)
#pragma unroll
            for (int r = 0; r < 4; ++r)
                outp[(size_t)(mf * 16 + orow + r) * 512 + nf * 16 + frow] =
                    acc[mf][nf][r] + bv[nf];
}

extern "C" void kernel_launch(void* const* d_in, const int* in_sizes, int n_in,
                              void* d_out, int out_size, void* d_ws, size_t ws_size,
                              hipStream_t stream) {
    const float* X    = (const float*)d_in[0];
    const float* Wt   = (const float*)d_in[1];
    const float* Bias = (const float*)d_in[2];
    float* Out        = (float*)d_out;

    dim3 grid(2048);
    bgemm_bt_bias<<<grid, TB, 0, stream>>>(X, Wt, Bias, Out);
}